// Round 1
// 1553.970 us; speedup vs baseline: 3.6494x; 3.6494x over previous
//
#include <hip/hip_runtime.h>

typedef unsigned short u16t;
typedef __attribute__((ext_vector_type(4))) u16t us4;
typedef __attribute__((ext_vector_type(8))) u16t us8;
typedef __attribute__((ext_vector_type(8))) short mf8;   // MFMA operand: 8 bf16 (guide §3)
typedef __attribute__((ext_vector_type(4))) float f4;

#define BB 2
#define CCH 128
#define HHH 256
#define WWW 510
#define WFQ 256
#define HWP 130560                  // HHH*WWW
#define NROW 65536                  // BB*CCH*HHH
#define UPL 16777216L               // NROW*WFQ (one re or im plane, elements)
#define YPAD 512                    // W padded to 512 for aligned MFMA staging

__device__ __forceinline__ float u2f(u16t v){ return __uint_as_float(((unsigned)v)<<16); }
__device__ __forceinline__ u16t  f2u(float f){
  unsigned u = __float_as_uint(f);
  return (u16t)((u + 0x7fffu + ((u>>16)&1u)) >> 16);      // RNE f32->bf16
}
__device__ __forceinline__ float ldin(const void* p, long i, int f32){
  return f32 ? ((const float*)p)[i] : u2f(((const u16t*)p)[i]);
}
__device__ __forceinline__ float sigm(float z){ return 1.f/(1.f+__expf(-z)); }
__device__ __forceinline__ f4 z4(){ f4 v; v[0]=0.f;v[1]=0.f;v[2]=0.f;v[3]=0.f; return v; }

// MFMA wrapper: D = A(16x32) * B(32x16) + C, bf16 inputs, f32 acc.
// A frag: lane l elem j = A[l&15][(l>>4)*8+j]; B frag: B[(l>>4)*8+j][l&15];
// D: col=lane&15, row=(lane>>4)*4+reg  [guide §3, measured m89/m91; b128-frag layout per m92/m97]
__device__ __forceinline__ f4 MF(us8 a, us8 b, f4 c){
  return __builtin_amdgcn_mfma_f32_16x16x32_bf16((mf8)a, (mf8)b, c, 0, 0, 0);
}

// ---- swizzled [rows][32] bf16 LDS tile helpers -------------------------------
// element group = 8 bf16 (16B). slot = k>>3 (0..3), stored at slot^(row&3).
// frag read: one ds_read_b128 per operand, bank-conflict at b128 floor.
__device__ __forceinline__ us8 frg(const u16t* tile, int row, int g){
  return *(const us8*)(tile + (row<<5) + (((g)^(row&3))<<3));
}
// natural-layout stage: copy R rows x 32 cols from src(base,pitch) into swizzled tile.
__device__ __forceinline__ void stg(u16t* __restrict__ tile, const u16t* __restrict__ src,
                                    long base, int pitch, int nu, int t){
  #pragma unroll
  for(int i=0;i<nu;i++){
    int e = t + 256*i;
    int row = e>>2, slot = e&3;
    us8 v = *(const us8*)(src + base + (long)row*pitch + (slot<<3));
    *(us8*)(tile + (row<<5) + ((slot^(row&3))<<3)) = v;
  }
}

// ---------------------------------------------------------------- detect dtype
__global__ void k_detect(const void* __restrict__ g, int* __restrict__ flag){
  __shared__ int cnt[256];
  int t = threadIdx.x;
  const u16t* pb = (const u16t*)g;
  int c = 0;
  for(int i=0;i<16;i++){
    int idx = t*16 + i;
    float v = u2f(pb[2*idx]);
    unsigned bits = __float_as_uint(v);
    int ex = (bits>>23)&0xff;
    if(ex >= 117 && ex <= 137) c++;
  }
  cnt[t]=c; __syncthreads();
  for(int s=128;s>0;s>>=1){ if(t<s) cnt[t]+=cnt[t+s]; __syncthreads(); }
  if(t==0) *flag = (cnt[0] < 2048) ? 1 : 0;
}

// ---------------------------------------------------------------- tables (bf16 hi/lo, operand-ready orientation)
__device__ __forceinline__ void hl(u16t* ph, u16t* pl, long i, float v){
  u16t h = f2u(v); ph[i] = h;
  pl[i] = f2u(v - u2f(h));
}
__global__ void k_tables2(u16t* twch, u16t* twcl, u16t* twsh, u16t* twsl,
                          u16t* thch, u16t* thcl, u16t* thsh, u16t* thsl,
                          u16t* tich, u16t* ticl, u16t* tish, u16t* tisl){
  long idx = (long)blockIdx.x*256 + threadIdx.x;   // 0..131071
  const float s510 = rsqrtf(510.0f);
  const float TP = 6.283185307179586f;
  {
    // forward rfft_W tables, B-layout [n=256][w=512]
    int n = (int)(idx>>9), w = (int)(idx&511);
    float c = 0.f, s = 0.f;
    if(w < 510){
      float ang = (TP/510.0f)*(float)((w*n)%510);
      c =  cosf(ang)*s510;
      s = -sinf(ang)*s510;
    }
    hl(twch, twcl, idx, c);
    hl(twsh, twsl, idx, s);
  }
  if(idx < 65536){
    // H-FFT twiddles [m=256][k=256], scale 1/16, s stored positive (sign applied in epilogue)
    int m = (int)(idx>>8), k = (int)(idx&255);
    float ang = (TP/256.0f)*(float)((m*k)&255);
    hl(thch, thcl, idx, cosf(ang)*0.0625f);
    hl(thsh, thsl, idx, sinf(ang)*0.0625f);
  }
  {
    // inverse rfft_W tables, B-layout [w=512][k=256], hermitian-fold ck baked in
    int w = (int)(idx>>8), k = (int)(idx&255);
    float c = 0.f, s = 0.f;
    if(w < 510){
      float ck = (k==0 || k==255) ? 1.0f : 2.0f;
      float ang = (TP/510.0f)*(float)((k*w)%510);
      c =  ck*cosf(ang)*s510;
      s = -ck*sinf(ang)*s510;
    }
    hl(tich, ticl, idx, c);
    hl(tish, tisl, idx, s);
  }
}

// zero the two pad columns of Y [65536][512]
__global__ void k_zpad(u16t* __restrict__ Y){
  int i = blockIdx.x*256 + threadIdx.x;   // 0..131071
  long row = i>>1;
  Y[row*YPAD + 510 + (i&1)] = 0;
}

// ---------------------------------------------------------------- 1x1 conv (MFMA)
// Y[(b,o,h)][w(512pad)] = sum_c W[o][c] * X[(b,c)][hw] + bias[o]
// A = W bf16 (as before); B = X split hi/lo (parity with f32-data path). 128x128 tile.
__global__ __launch_bounds__(256) void k_conv2(const void* __restrict__ in,
    const void* __restrict__ wmat, const void* __restrict__ bias,
    const int* __restrict__ flagp, u16t* __restrict__ Y){
  __shared__ __align__(16) u16t Aw[4096], Bh[4096], Bl[4096];
  __shared__ float sb[128];
  int f32 = *flagp;
  int t=threadIdx.x, l=t&63, wid=t>>6, wr=wid>>1, wc=wid&1;
  int hw0 = blockIdx.x*128, b = blockIdx.y;
  if(t<128) sb[t] = ldin(bias, t, f32);
  long inb = (long)b*CCH*HWP;
  f4 acc[4][4];
  #pragma unroll
  for(int i=0;i<4;i++) for(int j=0;j<4;j++) acc[i][j]=z4();
  for(int c0=0;c0<128;c0+=32){
    __syncthreads();
    // A: weights tile [o=128][c=32]
    #pragma unroll
    for(int i=0;i<2;i++){
      int e = t + 256*i; int row = e>>2, slot = e&3;
      u16t tmp[8];
      #pragma unroll
      for(int j=0;j<8;j++) tmp[j] = f2u(ldin(wmat, (long)row*128 + c0 + (slot<<3) + j, f32));
      *(us8*)(Aw + (row<<5) + ((slot^(row&3))<<3)) = *(us8*)tmp;
    }
    // B: X^T tile [hw=128][c=32], register-gather transpose, hi/lo split
    {
      int n = t&127, kb = (t>>7)*16;
      u16t th[16], tl[16];
      #pragma unroll
      for(int j=0;j<16;j++){
        float v = ldin(in, inb + (long)(c0+kb+j)*HWP + hw0 + n, f32);
        u16t h = f2u(v); th[j]=h;
        tl[j] = f2u(v - u2f(h));
      }
      int s0 = kb>>3;
      *(us8*)(Bh + (n<<5) + (((s0  )^(n&3))<<3)) = *(us8*)&th[0];
      *(us8*)(Bh + (n<<5) + (((s0+1)^(n&3))<<3)) = *(us8*)&th[8];
      *(us8*)(Bl + (n<<5) + (((s0  )^(n&3))<<3)) = *(us8*)&tl[0];
      *(us8*)(Bl + (n<<5) + (((s0+1)^(n&3))<<3)) = *(us8*)&tl[8];
    }
    __syncthreads();
    int lr=l&15, g=l>>4;
    us8 a[4];
    #pragma unroll
    for(int mm=0;mm<4;mm++) a[mm]=frg(Aw, wr*64+mm*16+lr, g);
    #pragma unroll
    for(int nn=0;nn<4;nn++){
      int rn = wc*64+nn*16+lr;
      us8 bh=frg(Bh,rn,g), bl=frg(Bl,rn,g);
      #pragma unroll
      for(int mm=0;mm<4;mm++){
        acc[mm][nn]=MF(a[mm],bh,acc[mm][nn]);
        acc[mm][nn]=MF(a[mm],bl,acc[mm][nn]);
      }
    }
  }
  int lr=l&15, g=l>>4;
  #pragma unroll
  for(int nn=0;nn<4;nn++){
    int hw = hw0 + wc*64 + nn*16 + lr;
    int h = hw/510, w = hw - h*510;
    #pragma unroll
    for(int mm=0;mm<4;mm++){
      #pragma unroll
      for(int r=0;r<4;r++){
        int o = wr*64 + mm*16 + (g<<2) + r;
        Y[((long)(b*128 + o)*256 + h)*YPAD + w] = f2u(acc[mm][nn][r] + sb[o]);
      }
    }
  }
}

// ---------------------------------------------------------------- rfft along W (MFMA)
// Gr/Gi[row][n] = sum_w Y[row][w]*tw{c,s}[n][w]; output written TRANSPOSED per plane:
// Grt[plane][n][h].  A = Y natural, B = tables (hi/lo). 128x128 tile, K=512.
__global__ __launch_bounds__(256) void k_rfft2(const u16t* __restrict__ Y,
    const u16t* __restrict__ twch, const u16t* __restrict__ twcl,
    const u16t* __restrict__ twsh, const u16t* __restrict__ twsl,
    u16t* __restrict__ Grt, u16t* __restrict__ Git){
  __shared__ __align__(16) u16t At[4096], Bch[4096], Bcl[4096], Bsh[4096], Bsl[4096];
  int t=threadIdx.x, l=t&63, wid=t>>6, wr=wid>>1, wc=wid&1;
  int m0 = blockIdx.x*128, n0 = blockIdx.y*128;
  f4 accr[4][4], acci[4][4];
  #pragma unroll
  for(int i=0;i<4;i++) for(int j=0;j<4;j++){ accr[i][j]=z4(); acci[i][j]=z4(); }
  for(int k0=0;k0<512;k0+=32){
    __syncthreads();
    stg(At,  Y,    (long)m0*YPAD + k0, YPAD, 2, t);
    stg(Bch, twch, (long)n0*512  + k0, 512,  2, t);
    stg(Bcl, twcl, (long)n0*512  + k0, 512,  2, t);
    stg(Bsh, twsh, (long)n0*512  + k0, 512,  2, t);
    stg(Bsl, twsl, (long)n0*512  + k0, 512,  2, t);
    __syncthreads();
    int lr=l&15, g=l>>4;
    us8 a[4];
    #pragma unroll
    for(int mm=0;mm<4;mm++) a[mm]=frg(At, wr*64+mm*16+lr, g);
    #pragma unroll
    for(int nn=0;nn<4;nn++){
      int rn = wc*64+nn*16+lr;
      us8 bch=frg(Bch,rn,g), bcl=frg(Bcl,rn,g), bsh=frg(Bsh,rn,g), bsl=frg(Bsl,rn,g);
      #pragma unroll
      for(int mm=0;mm<4;mm++){
        accr[mm][nn]=MF(a[mm],bch,accr[mm][nn]); accr[mm][nn]=MF(a[mm],bcl,accr[mm][nn]);
        acci[mm][nn]=MF(a[mm],bsh,acci[mm][nn]); acci[mm][nn]=MF(a[mm],bsl,acci[mm][nn]);
      }
    }
  }
  int plane = blockIdx.x>>1;
  int h0 = (blockIdx.x&1)<<7;
  int lr=l&15, g=l>>4;
  #pragma unroll
  for(int nn=0;nn<4;nn++){
    int n = n0 + wc*64 + nn*16 + lr;
    #pragma unroll
    for(int mm=0;mm<4;mm++){
      int hh = h0 + wr*64 + mm*16 + (g<<2);
      long o = (long)plane*65536 + (long)n*256 + hh;
      us4 pr, pi;
      #pragma unroll
      for(int r=0;r<4;r++){ pr[r]=f2u(accr[mm][nn][r]); pi[r]=f2u(acci[mm][nn][r]); }
      *(us4*)(Grt+o)=pr; *(us4*)(Git+o)=pi;
    }
  }
}

// ---------------------------------------------------------------- FFT/iFFT along H (MFMA)
// D[m][n] = sum_h (C - i*sgn*S)[m][h] * (Gr+iGi)[h][n], per plane.
// P1=C*Gr P2=S*Gi P3=C*Gi P4=S*Gr; Or=P1+sgn*P2, Oi=P3-sgn*P4.
// A = th tables (hi/lo), B = plane in transposed layout [n][h] (natural copy).
// fwd (tr_out=1): apply filter, write transposed. inv (tr_out=0): write natural.
__global__ __launch_bounds__(256) void k_ffth2(
    const u16t* __restrict__ Br_, const u16t* __restrict__ Bi_,
    const u16t* __restrict__ ach_, const u16t* __restrict__ acl_,
    const u16t* __restrict__ ash_, const u16t* __restrict__ asl_,
    float sgn, int tr_out, const void* __restrict__ filt, const int* __restrict__ flagp,
    u16t* __restrict__ Or_, u16t* __restrict__ Oi_){
  __shared__ __align__(16) u16t Ach[2048], Acl[2048], Ash[2048], Asl[2048], Bgr[2048], Bgi[2048];
  int t=threadIdx.x, l=t&63, wid=t>>6, wr=wid>>1, wc=wid&1;
  int m0=blockIdx.x*64, n0=blockIdx.y*64, plane=blockIdx.z;
  long pbase=(long)plane*65536;
  f4 P1[2][2],P2[2][2],P3[2][2],P4[2][2];
  #pragma unroll
  for(int i=0;i<2;i++) for(int j=0;j<2;j++){ P1[i][j]=z4();P2[i][j]=z4();P3[i][j]=z4();P4[i][j]=z4(); }
  for(int k0=0;k0<256;k0+=32){
    __syncthreads();
    stg(Ach, ach_, (long)m0*256+k0, 256, 1, t);
    stg(Acl, acl_, (long)m0*256+k0, 256, 1, t);
    stg(Ash, ash_, (long)m0*256+k0, 256, 1, t);
    stg(Asl, asl_, (long)m0*256+k0, 256, 1, t);
    stg(Bgr, Br_, pbase+(long)n0*256+k0, 256, 1, t);
    stg(Bgi, Bi_, pbase+(long)n0*256+k0, 256, 1, t);
    __syncthreads();
    int lr=l&15, g=l>>4;
    us8 fch[2],fcl[2],fsh[2],fsl[2];
    #pragma unroll
    for(int mm=0;mm<2;mm++){
      int rr=wr*32+mm*16+lr;
      fch[mm]=frg(Ach,rr,g); fcl[mm]=frg(Acl,rr,g); fsh[mm]=frg(Ash,rr,g); fsl[mm]=frg(Asl,rr,g);
    }
    #pragma unroll
    for(int nn=0;nn<2;nn++){
      int rn=wc*32+nn*16+lr;
      us8 bgr=frg(Bgr,rn,g), bgi=frg(Bgi,rn,g);
      #pragma unroll
      for(int mm=0;mm<2;mm++){
        P1[mm][nn]=MF(fch[mm],bgr,P1[mm][nn]); P1[mm][nn]=MF(fcl[mm],bgr,P1[mm][nn]);
        P2[mm][nn]=MF(fsh[mm],bgi,P2[mm][nn]); P2[mm][nn]=MF(fsl[mm],bgi,P2[mm][nn]);
        P3[mm][nn]=MF(fch[mm],bgi,P3[mm][nn]); P3[mm][nn]=MF(fcl[mm],bgi,P3[mm][nn]);
        P4[mm][nn]=MF(fsh[mm],bgr,P4[mm][nn]); P4[mm][nn]=MF(fsl[mm],bgr,P4[mm][nn]);
      }
    }
  }
  int f32 = filt ? *flagp : 0;
  int lr=l&15, g=l>>4;
  int c_ch = plane & 127;
  #pragma unroll
  for(int nn=0;nn<2;nn++){
    int n = n0 + wc*32 + nn*16 + lr;
    #pragma unroll
    for(int mm=0;mm<2;mm++){
      int mb = m0 + wr*32 + mm*16 + (g<<2);
      float vr[4], vi[4];
      #pragma unroll
      for(int r=0;r<4;r++){
        vr[r] = P1[mm][nn][r] + sgn*P2[mm][nn][r];
        vi[r] = P3[mm][nn][r] - sgn*P4[mm][nn][r];
      }
      if(filt){
        #pragma unroll
        for(int r=0;r<4;r++){
          long fi = (((long)c_ch*256 + (mb+r))*256 + n)*2;
          float fwr=ldin(filt,fi,f32), fwi=ldin(filt,fi+1,f32);
          float a=vr[r], b=vi[r];
          vr[r]=a*fwr-b*fwi; vi[r]=a*fwi+b*fwr;
        }
      }
      if(tr_out){
        us4 pr, pi;
        #pragma unroll
        for(int r=0;r<4;r++){ pr[r]=f2u(vr[r]); pi[r]=f2u(vi[r]); }
        *(us4*)(Or_ + pbase + (long)n*256 + mb) = pr;
        *(us4*)(Oi_ + pbase + (long)n*256 + mb) = pi;
      } else {
        #pragma unroll
        for(int r=0;r<4;r++){
          Or_[pbase + (long)(mb+r)*256 + n] = f2u(vr[r]);
          Oi_[pbase + (long)(mb+r)*256 + n] = f2u(vi[r]);
        }
      }
    }
  }
}

// ---------------------------------------------------------------- row variance (transposed layout)
// var over kw of G2[.][kh] = column kh of G2t -> coalesced row walks.
__global__ __launch_bounds__(1024) void k_var2(const u16t* __restrict__ Grt,
    const u16t* __restrict__ Git, float* __restrict__ rinv){
  __shared__ float rs[1024], is_[1024], qs[1024];
  int plane = blockIdx.x, t = threadIdx.x;
  int kh = t & 255, part = t >> 8;
  long base = (long)plane*65536 + kh;
  float sr=0.f, si=0.f, s2=0.f;
  #pragma unroll 4
  for(int q=0;q<64;q++){
    long o = base + (long)(part*64+q)*256;
    float r = u2f(Grt[o]), im = u2f(Git[o]);
    sr += r; si += im; s2 += r*r + im*im;
  }
  rs[t]=sr; is_[t]=si; qs[t]=s2;
  __syncthreads();
  if(t<256){
    sr = rs[t]+rs[t+256]+rs[t+512]+rs[t+768];
    si = is_[t]+is_[t+256]+is_[t+512]+is_[t+768];
    s2 = qs[t]+qs[t+256]+qs[t+512]+qs[t+768];
    float mr = sr*(1.f/256.f), mi = si*(1.f/256.f);
    float v = s2*(1.f/256.f) - mr*mr - mi*mi;
    rinv[plane*256 + kh] = rsqrtf(6.283185307179586f * fmaxf(v, 1e-20f));
  }
}

// ---------------------------------------------------------------- scores (MFMA) + sigmoid
// scores[m][n] = sum_k G[k][m]*X[k][n] (complex, no conj). A=G2t natural, B=X2t natural.
// accr = P1-P2, acci = P3+P4. Output transposed (attenT[n][m]) for the inverse H pass.
__global__ __launch_bounds__(256) void k_scores2(
    const u16t* __restrict__ Agr_, const u16t* __restrict__ Agi_,
    const u16t* __restrict__ Bxr_, const u16t* __restrict__ Bxi_,
    const float* __restrict__ rinv, u16t* __restrict__ Sr_, u16t* __restrict__ Si_){
  __shared__ __align__(16) u16t Agr[2048], Agi[2048], Bxr[2048], Bxi[2048];
  int t=threadIdx.x, l=t&63, wid=t>>6, wr=wid>>1, wc=wid&1;
  int m0=blockIdx.x*64, n0=blockIdx.y*64, plane=blockIdx.z;
  long pbase=(long)plane*65536;
  f4 P1[2][2],P2[2][2],P3[2][2],P4[2][2];
  #pragma unroll
  for(int i=0;i<2;i++) for(int j=0;j<2;j++){ P1[i][j]=z4();P2[i][j]=z4();P3[i][j]=z4();P4[i][j]=z4(); }
  for(int k0=0;k0<256;k0+=32){
    __syncthreads();
    stg(Agr, Agr_, pbase+(long)m0*256+k0, 256, 1, t);
    stg(Agi, Agi_, pbase+(long)m0*256+k0, 256, 1, t);
    stg(Bxr, Bxr_, pbase+(long)n0*256+k0, 256, 1, t);
    stg(Bxi, Bxi_, pbase+(long)n0*256+k0, 256, 1, t);
    __syncthreads();
    int lr=l&15, g=l>>4;
    us8 agr[2], agi[2];
    #pragma unroll
    for(int mm=0;mm<2;mm++){
      int rr=wr*32+mm*16+lr;
      agr[mm]=frg(Agr,rr,g); agi[mm]=frg(Agi,rr,g);
    }
    #pragma unroll
    for(int nn=0;nn<2;nn++){
      int rn=wc*32+nn*16+lr;
      us8 bxr=frg(Bxr,rn,g), bxi=frg(Bxi,rn,g);
      #pragma unroll
      for(int mm=0;mm<2;mm++){
        P1[mm][nn]=MF(agr[mm],bxr,P1[mm][nn]);
        P2[mm][nn]=MF(agi[mm],bxi,P2[mm][nn]);
        P3[mm][nn]=MF(agr[mm],bxi,P3[mm][nn]);
        P4[mm][nn]=MF(agi[mm],bxr,P4[mm][nn]);
      }
    }
  }
  int lr=l&15, g=l>>4;
  #pragma unroll
  for(int nn=0;nn<2;nn++){
    int n = n0 + wc*32 + nn*16 + lr;
    #pragma unroll
    for(int mm=0;mm<2;mm++){
      int mb = m0 + wr*32 + mm*16 + (g<<2);
      us4 pr, pi;
      #pragma unroll
      for(int r=0;r<4;r++){
        float rv = rinv[(plane<<8) + mb + r];
        pr[r] = f2u(sigm((P1[mm][nn][r]-P2[mm][nn][r])*rv));
        pi[r] = f2u(sigm((P3[mm][nn][r]+P4[mm][nn][r])*rv));
      }
      *(us4*)(Sr_ + pbase + (long)n*256 + mb) = pr;
      *(us4*)(Si_ + pbase + (long)n*256 + mb) = pi;
    }
  }
}

// ---------------------------------------------------------------- irfft along W (MFMA) + add x
// R[row][w] = sum_k Tr[row][k]*tic[k][w] + Ti[row][k]*tis[k][w] + x. f32 out.
__global__ __launch_bounds__(256) void k_irfft2(
    const u16t* __restrict__ Tr, const u16t* __restrict__ Ti,
    const u16t* __restrict__ tich, const u16t* __restrict__ ticl,
    const u16t* __restrict__ tish, const u16t* __restrict__ tisl,
    const void* __restrict__ xin, const int* __restrict__ flagp, float* __restrict__ R){
  __shared__ __align__(16) u16t Ar[4096], Ai[4096], Bch[4096], Bcl[4096], Bsh[4096], Bsl[4096];
  int t=threadIdx.x, l=t&63, wid=t>>6, wr=wid>>1, wc=wid&1;
  int m0=blockIdx.x*128, n0=blockIdx.y*128;
  f4 acc[4][4];
  #pragma unroll
  for(int i=0;i<4;i++) for(int j=0;j<4;j++) acc[i][j]=z4();
  for(int k0=0;k0<256;k0+=32){
    __syncthreads();
    stg(Ar,  Tr,   (long)m0*256+k0, 256, 2, t);
    stg(Ai,  Ti,   (long)m0*256+k0, 256, 2, t);
    stg(Bch, tich, (long)n0*256+k0, 256, 2, t);
    stg(Bcl, ticl, (long)n0*256+k0, 256, 2, t);
    stg(Bsh, tish, (long)n0*256+k0, 256, 2, t);
    stg(Bsl, tisl, (long)n0*256+k0, 256, 2, t);
    __syncthreads();
    int lr=l&15, g=l>>4;
    us8 ar[4], ai[4];
    #pragma unroll
    for(int mm=0;mm<4;mm++){
      int rr = wr*64+mm*16+lr;
      ar[mm]=frg(Ar,rr,g); ai[mm]=frg(Ai,rr,g);
    }
    #pragma unroll
    for(int nn=0;nn<4;nn++){
      int rn = wc*64+nn*16+lr;
      us8 bch=frg(Bch,rn,g), bcl=frg(Bcl,rn,g), bsh=frg(Bsh,rn,g), bsl=frg(Bsl,rn,g);
      #pragma unroll
      for(int mm=0;mm<4;mm++){
        acc[mm][nn]=MF(ar[mm],bch,acc[mm][nn]); acc[mm][nn]=MF(ar[mm],bcl,acc[mm][nn]);
        acc[mm][nn]=MF(ai[mm],bsh,acc[mm][nn]); acc[mm][nn]=MF(ai[mm],bsl,acc[mm][nn]);
      }
    }
  }
  int f32=*flagp;
  int lr=l&15, g=l>>4;
  #pragma unroll
  for(int nn=0;nn<4;nn++){
    int w = n0 + wc*64 + nn*16 + lr;
    if(w >= 510) continue;
    #pragma unroll
    for(int mm=0;mm<4;mm++){
      int row0 = m0 + wr*64 + mm*16 + (g<<2);
      #pragma unroll
      for(int r=0;r<4;r++){
        long o = (long)(row0+r)*510 + w;
        R[o] = acc[mm][nn][r] + ldin(xin, o, f32);
      }
    }
  }
}

// ---------------------------------------------------------------- channel LayerNorm
__global__ __launch_bounds__(256) void k_ln(const float* __restrict__ R,
    const void* __restrict__ gamma, const void* __restrict__ beta,
    const int* __restrict__ flagp, void* __restrict__ out){
  int f32 = *flagp;
  int p = blockIdx.x*256 + threadIdx.x;
  int b = p / HWP, hw = p % HWP;
  long base = (long)b*CCH*HWP + hw;
  float sum=0.f, sq=0.f;
  for(int c=0;c<CCH;c++){
    float v = R[base + (long)c*HWP];
    sum += v; sq += v*v;
  }
  float mu = sum*(1.f/128.f);
  float var = sq*(1.f/128.f) - mu*mu;
  float inv = rsqrtf(fmaxf(var,0.f) + 1e-6f);
  for(int c=0;c<CCH;c++){
    float v = (R[base + (long)c*HWP] - mu)*inv;
    float o = ldin(gamma,c,f32)*v + ldin(beta,c,f32);
    long oi = base + (long)c*HWP;
    if(f32) ((float*)out)[oi] = o;
    else    ((u16t*)out)[oi]  = f2u(o);
  }
}

// ================================================================ launcher
extern "C" void kernel_launch(void* const* d_in, const int* in_sizes, int n_in,
                              void* d_out, int out_size, void* d_ws, size_t ws_size,
                              hipStream_t stream) {
  const void* g   = d_in[0];
  const void* x   = d_in[1];
  const void* wg  = d_in[2];
  const void* bg  = d_in[3];
  const void* wx  = d_in[4];
  const void* bx  = d_in[5];
  const void* fg  = d_in[6];
  const void* fx  = d_in[7];
  const void* gam = d_in[8];
  const void* bet = d_in[9];

  // workspace carve (~204.2 MB)
  u16t* Y  = (u16t*)d_ws;            // [65536][512] padded conv out; later X2t; later part of R
  u16t* Bq = Y  + 33554432L;         // G1t / attenT (re,im = +0, +UPL)
  u16t* Cq = Bq + 33554432L;         // G2t / T     (re,im)
  char* pp = (char*)d_ws + 201326592L;
  float* rinv = (float*)pp; pp += 262144L;
  u16t* twch=(u16t*)pp; pp+=262144L;  u16t* twcl=(u16t*)pp; pp+=262144L;
  u16t* twsh=(u16t*)pp; pp+=262144L;  u16t* twsl=(u16t*)pp; pp+=262144L;
  u16t* thch=(u16t*)pp; pp+=131072L;  u16t* thcl=(u16t*)pp; pp+=131072L;
  u16t* thsh=(u16t*)pp; pp+=131072L;  u16t* thsl=(u16t*)pp; pp+=131072L;
  u16t* tich=(u16t*)pp; pp+=262144L;  u16t* ticl=(u16t*)pp; pp+=262144L;
  u16t* tish=(u16t*)pp; pp+=262144L;  u16t* tisl=(u16t*)pp; pp+=262144L;
  int* flag = (int*)pp;
  float* R  = (float*)d_ws;          // overlays Y+Bq (133.7MB <= 134.2MB; both dead by then)

  k_detect <<<1,256,0,stream>>>(g, flag);
  k_tables2<<<512,256,0,stream>>>(twch,twcl,twsh,twsl,thch,thcl,thsh,thsl,tich,ticl,tish,tisl);
  k_zpad   <<<512,256,0,stream>>>(Y);

  // --- g path: conv -> rfft_W (writes G1t) -> FFT_H * filter (writes G2t) => Cq
  k_conv2<<<dim3(1020,2),256,0,stream>>>(g, wg, bg, flag, Y);
  k_rfft2<<<dim3(512,2),256,0,stream>>>(Y, twch,twcl,twsh,twsl, Bq, Bq+UPL);
  k_ffth2<<<dim3(4,4,256),256,0,stream>>>(Bq, Bq+UPL, thch,thcl,thsh,thsl, 1.f, 1, fg, flag, Cq, Cq+UPL);

  // --- x path => X2t into Y region (Y dead after rfft)
  k_conv2<<<dim3(1020,2),256,0,stream>>>(x, wx, bx, flag, Y);
  k_rfft2<<<dim3(512,2),256,0,stream>>>(Y, twch,twcl,twsh,twsl, Bq, Bq+UPL);
  k_ffth2<<<dim3(4,4,256),256,0,stream>>>(Bq, Bq+UPL, thch,thcl,thsh,thsl, 1.f, 1, fx, flag, Y, Y+UPL);

  // --- variance of G2 rows (columns of G2t) -> rinv
  k_var2<<<256,1024,0,stream>>>(Cq, Cq+UPL, rinv);

  // --- scores + sigmoid => attenT in Bq
  k_scores2<<<dim3(4,4,256),256,0,stream>>>(Cq, Cq+UPL, Y, Y+UPL, rinv, Bq, Bq+UPL);

  // --- inverse FFT along H => T (natural layout) in Cq
  k_ffth2<<<dim3(4,4,256),256,0,stream>>>(Bq, Bq+UPL, thch,thcl,thsh,thsl, -1.f, 0, nullptr, flag, Cq, Cq+UPL);

  // --- inverse rfft along W, + x  => R (f32)
  k_irfft2<<<dim3(512,4),256,0,stream>>>(Cq, Cq+UPL, tich,ticl,tish,tisl, x, flag, R);

  // --- channel LayerNorm => out
  k_ln<<<1020,256,0,stream>>>(R, gam, bet, flag, d_out);
}

// Round 2
// 1390.310 us; speedup vs baseline: 4.0790x; 1.1177x over previous
//
#include <hip/hip_runtime.h>

typedef unsigned short u16t;
typedef __attribute__((ext_vector_type(4))) u16t us4;
typedef __attribute__((ext_vector_type(8))) u16t us8;
typedef __attribute__((ext_vector_type(8))) short mf8;   // MFMA operand: 8 bf16 (guide §3)
typedef __attribute__((ext_vector_type(4))) float f4;

#define BB 2
#define CCH 128
#define HHH 256
#define WWW 510
#define WFQ 256
#define HWP 130560                  // HHH*WWW
#define NROW 65536                  // BB*CCH*HHH
#define UPL 16777216L               // NROW*WFQ (one re or im plane, elements)
#define YPAD 512                    // W padded to 512 for aligned MFMA staging

__device__ __forceinline__ float u2f(u16t v){ return __uint_as_float(((unsigned)v)<<16); }
__device__ __forceinline__ u16t  f2u(float f){
  unsigned u = __float_as_uint(f);
  return (u16t)((u + 0x7fffu + ((u>>16)&1u)) >> 16);      // RNE f32->bf16
}
__device__ __forceinline__ float ldin(const void* p, long i, int f32){
  return f32 ? ((const float*)p)[i] : u2f(((const u16t*)p)[i]);
}
__device__ __forceinline__ float sigm(float z){ return 1.f/(1.f+__expf(-z)); }
__device__ __forceinline__ f4 z4(){ f4 v; v[0]=0.f;v[1]=0.f;v[2]=0.f;v[3]=0.f; return v; }

// MFMA wrapper: D = A(16x32) * B(32x16) + C, bf16 inputs, f32 acc.
__device__ __forceinline__ f4 MF(us8 a, us8 b, f4 c){
  return __builtin_amdgcn_mfma_f32_16x16x32_bf16((mf8)a, (mf8)b, c, 0, 0, 0);
}

// ---- swizzled [rows][32] bf16 LDS tile helpers -------------------------------
// tile row = 64B. bank base of a row = 16*(row&1); slot xor must decorrelate
// rows r, r+4 -> use (row>>1)&3 (2-way max per 16-lane phase; 2-way is free).
__device__ __forceinline__ int swz(int row){ return (row>>1)&3; }

__device__ __forceinline__ us8 frg(const u16t* tile, int row, int g){
  return *(const us8*)(tile + (row<<5) + (((g)^swz(row))<<3));
}
// T14 split staging: ldt issues global loads into regs; stt writes them swizzled.
__device__ __forceinline__ void ldt(us8* v, const u16t* __restrict__ src,
                                    long base, int pitch, int nu, int t){
  #pragma unroll
  for(int i=0;i<nu;i++){
    int e = t + 256*i;
    int row = e>>2, slot = e&3;
    v[i] = *(const us8*)(src + base + (long)row*pitch + (slot<<3));
  }
}
__device__ __forceinline__ void stt(u16t* __restrict__ tile, const us8* v, int nu, int t){
  #pragma unroll
  for(int i=0;i<nu;i++){
    int e = t + 256*i;
    int row = e>>2, slot = e&3;
    *(us8*)(tile + (row<<5) + ((slot^swz(row))<<3)) = v[i];
  }
}

// ---------------------------------------------------------------- detect dtype
__global__ void k_detect(const void* __restrict__ g, int* __restrict__ flag){
  __shared__ int cnt[256];
  int t = threadIdx.x;
  const u16t* pb = (const u16t*)g;
  int c = 0;
  for(int i=0;i<16;i++){
    int idx = t*16 + i;
    float v = u2f(pb[2*idx]);
    unsigned bits = __float_as_uint(v);
    int ex = (bits>>23)&0xff;
    if(ex >= 117 && ex <= 137) c++;
  }
  cnt[t]=c; __syncthreads();
  for(int s=128;s>0;s>>=1){ if(t<s) cnt[t]+=cnt[t+s]; __syncthreads(); }
  if(t==0) *flag = (cnt[0] < 2048) ? 1 : 0;
}

// ---------------------------------------------------------------- tables (bf16 hi/lo)
__device__ __forceinline__ void hl(u16t* ph, u16t* pl, long i, float v){
  u16t h = f2u(v); ph[i] = h;
  pl[i] = f2u(v - u2f(h));
}
__global__ void k_tables2(u16t* twch, u16t* twcl, u16t* twsh, u16t* twsl,
                          u16t* thch, u16t* thcl, u16t* thsh, u16t* thsl,
                          u16t* tich, u16t* ticl, u16t* tish, u16t* tisl){
  long idx = (long)blockIdx.x*256 + threadIdx.x;   // 0..131071
  const float s510 = rsqrtf(510.0f);
  const float TP = 6.283185307179586f;
  {
    // forward rfft_W tables, B-layout [n=256][w=512]
    int n = (int)(idx>>9), w = (int)(idx&511);
    float c = 0.f, s = 0.f;
    if(w < 510){
      float ang = (TP/510.0f)*(float)((w*n)%510);
      c =  cosf(ang)*s510;
      s = -sinf(ang)*s510;
    }
    hl(twch, twcl, idx, c);
    hl(twsh, twsl, idx, s);
  }
  if(idx < 65536){
    // H-FFT twiddles [m=256][k=256], scale 1/16
    int m = (int)(idx>>8), k = (int)(idx&255);
    float ang = (TP/256.0f)*(float)((m*k)&255);
    hl(thch, thcl, idx, cosf(ang)*0.0625f);
    hl(thsh, thsl, idx, sinf(ang)*0.0625f);
  }
  {
    // inverse rfft_W tables, B-layout [w=512][k=256], hermitian-fold ck baked in
    int w = (int)(idx>>8), k = (int)(idx&255);
    float c = 0.f, s = 0.f;
    if(w < 510){
      float ck = (k==0 || k==255) ? 1.0f : 2.0f;
      float ang = (TP/510.0f)*(float)((k*w)%510);
      c =  ck*cosf(ang)*s510;
      s = -ck*sinf(ang)*s510;
    }
    hl(tich, ticl, idx, c);
    hl(tish, tisl, idx, s);
  }
}

// zero the two pad columns of Y [65536][512]
__global__ void k_zpad(u16t* __restrict__ Y){
  int i = blockIdx.x*256 + threadIdx.x;   // 0..131071
  long row = i>>1;
  Y[row*YPAD + 510 + (i&1)] = 0;
}

// ---------------------------------------------------------------- 1x1 conv (MFMA, T14)
__global__ __launch_bounds__(256) void k_conv2(const void* __restrict__ in,
    const void* __restrict__ wmat, const void* __restrict__ bias,
    const int* __restrict__ flagp, u16t* __restrict__ Y){
  __shared__ __align__(16) u16t Aw[4096], Bh[4096], Bl[4096];
  __shared__ float sb[128];
  int f32 = *flagp;
  int t=threadIdx.x, l=t&63, wid=t>>6, wr=wid>>1, wc=wid&1;
  int hw0 = blockIdx.x*128, b = blockIdx.y;
  if(t<128) sb[t] = ldin(bias, t, f32);
  long inb = (long)b*CCH*HWP;
  int bn = t&127, bkb = (t>>7)*16, bs0 = bkb>>3;
  f4 acc[4][4];
  #pragma unroll
  for(int i=0;i<4;i++) for(int j=0;j<4;j++) acc[i][j]=z4();
  float pa[16], pb[16];
  // prefetch c0 = 0
  #pragma unroll
  for(int i=0;i<2;i++){ int e=t+256*i; int row=e>>2, slot=e&3;
    #pragma unroll
    for(int j=0;j<8;j++) pa[i*8+j] = ldin(wmat, (long)row*128 + (slot<<3) + j, f32); }
  #pragma unroll
  for(int j=0;j<16;j++) pb[j] = ldin(in, inb + (long)(bkb+j)*HWP + hw0 + bn, f32);

  for(int c0=0;c0<128;c0+=32){
    __syncthreads();
    // store A (weights, hi only)
    #pragma unroll
    for(int i=0;i<2;i++){ int e=t+256*i; int row=e>>2, slot=e&3;
      u16t tmp[8];
      #pragma unroll
      for(int j=0;j<8;j++) tmp[j] = f2u(pa[i*8+j]);
      *(us8*)(Aw + (row<<5) + ((slot^swz(row))<<3)) = *(us8*)tmp; }
    // store B (data, hi/lo)
    {
      u16t th[16], tl[16];
      #pragma unroll
      for(int j=0;j<16;j++){ u16t h=f2u(pb[j]); th[j]=h; tl[j]=f2u(pb[j]-u2f(h)); }
      int sw = swz(bn);
      *(us8*)(Bh + (bn<<5) + (((bs0  )^sw)<<3)) = *(us8*)&th[0];
      *(us8*)(Bh + (bn<<5) + (((bs0+1)^sw)<<3)) = *(us8*)&th[8];
      *(us8*)(Bl + (bn<<5) + (((bs0  )^sw)<<3)) = *(us8*)&tl[0];
      *(us8*)(Bl + (bn<<5) + (((bs0+1)^sw)<<3)) = *(us8*)&tl[8];
    }
    if(c0+32 < 128){
      #pragma unroll
      for(int i=0;i<2;i++){ int e=t+256*i; int row=e>>2, slot=e&3;
        #pragma unroll
        for(int j=0;j<8;j++) pa[i*8+j] = ldin(wmat, (long)row*128 + c0+32 + (slot<<3) + j, f32); }
      #pragma unroll
      for(int j=0;j<16;j++) pb[j] = ldin(in, inb + (long)(c0+32+bkb+j)*HWP + hw0 + bn, f32);
    }
    __syncthreads();
    int lr=l&15, g=l>>4;
    us8 a[4];
    #pragma unroll
    for(int mm=0;mm<4;mm++) a[mm]=frg(Aw, wr*64+mm*16+lr, g);
    #pragma unroll
    for(int nn=0;nn<4;nn++){
      int rn = wc*64+nn*16+lr;
      us8 bh=frg(Bh,rn,g), bl=frg(Bl,rn,g);
      #pragma unroll
      for(int mm=0;mm<4;mm++){
        acc[mm][nn]=MF(a[mm],bh,acc[mm][nn]);
        acc[mm][nn]=MF(a[mm],bl,acc[mm][nn]);
      }
    }
  }
  int lr=l&15, g=l>>4;
  #pragma unroll
  for(int nn=0;nn<4;nn++){
    int hw = hw0 + wc*64 + nn*16 + lr;
    int h = hw/510, w = hw - h*510;
    #pragma unroll
    for(int mm=0;mm<4;mm++){
      #pragma unroll
      for(int r=0;r<4;r++){
        int o = wr*64 + mm*16 + (g<<2) + r;
        Y[((long)(b*128 + o)*256 + h)*YPAD + w] = f2u(acc[mm][nn][r] + sb[o]);
      }
    }
  }
}

// ---------------------------------------------------------------- rfft along W (MFMA, T14)
__global__ __launch_bounds__(256) void k_rfft2(const u16t* __restrict__ Y,
    const u16t* __restrict__ twch, const u16t* __restrict__ twcl,
    const u16t* __restrict__ twsh, const u16t* __restrict__ twsl,
    u16t* __restrict__ Grt, u16t* __restrict__ Git){
  __shared__ __align__(16) u16t At[4096], Bch[4096], Bcl[4096], Bsh[4096], Bsl[4096];
  int t=threadIdx.x, l=t&63, wid=t>>6, wr=wid>>1, wc=wid&1;
  int m0 = blockIdx.x*128, n0 = blockIdx.y*128;
  f4 accr[4][4], acci[4][4];
  #pragma unroll
  for(int i=0;i<4;i++) for(int j=0;j<4;j++){ accr[i][j]=z4(); acci[i][j]=z4(); }
  us8 pA[2], pC[2], pc2[2], pS[2], ps2[2];
  ldt(pA,  Y,    (long)m0*YPAD, YPAD, 2, t);
  ldt(pC,  twch, (long)n0*512,  512,  2, t);
  ldt(pc2, twcl, (long)n0*512,  512,  2, t);
  ldt(pS,  twsh, (long)n0*512,  512,  2, t);
  ldt(ps2, twsl, (long)n0*512,  512,  2, t);
  for(int k0=0;k0<512;k0+=32){
    __syncthreads();
    stt(At,pA,2,t); stt(Bch,pC,2,t); stt(Bcl,pc2,2,t); stt(Bsh,pS,2,t); stt(Bsl,ps2,2,t);
    if(k0+32 < 512){
      ldt(pA,  Y,    (long)m0*YPAD + k0+32, YPAD, 2, t);
      ldt(pC,  twch, (long)n0*512  + k0+32, 512,  2, t);
      ldt(pc2, twcl, (long)n0*512  + k0+32, 512,  2, t);
      ldt(pS,  twsh, (long)n0*512  + k0+32, 512,  2, t);
      ldt(ps2, twsl, (long)n0*512  + k0+32, 512,  2, t);
    }
    __syncthreads();
    int lr=l&15, g=l>>4;
    us8 a[4];
    #pragma unroll
    for(int mm=0;mm<4;mm++) a[mm]=frg(At, wr*64+mm*16+lr, g);
    #pragma unroll
    for(int nn=0;nn<4;nn++){
      int rn = wc*64+nn*16+lr;
      us8 bch=frg(Bch,rn,g), bcl=frg(Bcl,rn,g), bsh=frg(Bsh,rn,g), bsl=frg(Bsl,rn,g);
      #pragma unroll
      for(int mm=0;mm<4;mm++){
        accr[mm][nn]=MF(a[mm],bch,accr[mm][nn]); accr[mm][nn]=MF(a[mm],bcl,accr[mm][nn]);
        acci[mm][nn]=MF(a[mm],bsh,acci[mm][nn]); acci[mm][nn]=MF(a[mm],bsl,acci[mm][nn]);
      }
    }
  }
  int plane = blockIdx.x>>1;
  int h0 = (blockIdx.x&1)<<7;
  int lr=l&15, g=l>>4;
  #pragma unroll
  for(int nn=0;nn<4;nn++){
    int n = n0 + wc*64 + nn*16 + lr;
    #pragma unroll
    for(int mm=0;mm<4;mm++){
      int hh = h0 + wr*64 + mm*16 + (g<<2);
      long o = (long)plane*65536 + (long)n*256 + hh;
      us4 pr, pi;
      #pragma unroll
      for(int r=0;r<4;r++){ pr[r]=f2u(accr[mm][nn][r]); pi[r]=f2u(acci[mm][nn][r]); }
      *(us4*)(Grt+o)=pr; *(us4*)(Git+o)=pi;
    }
  }
}

// ---------------------------------------------------------------- FFT/iFFT along H (MFMA, T14)
// LO: use hi+lo tables (forward path); TR: write transposed + filter.
template<int LO, int TR>
__global__ __launch_bounds__(256) void k_ffth2(
    const u16t* __restrict__ Br_, const u16t* __restrict__ Bi_,
    const u16t* __restrict__ ach_, const u16t* __restrict__ acl_,
    const u16t* __restrict__ ash_, const u16t* __restrict__ asl_,
    float sgn, const void* __restrict__ filt, const int* __restrict__ flagp,
    u16t* __restrict__ Or_, u16t* __restrict__ Oi_){
  __shared__ __align__(16) u16t Ach[2048], Ash[2048], Bgr[2048], Bgi[2048];
  __shared__ __align__(16) u16t Acl[LO?2048:16], Asl[LO?2048:16];
  int t=threadIdx.x, l=t&63, wid=t>>6, wr=wid>>1, wc=wid&1;
  int m0=blockIdx.x*64, n0=blockIdx.y*64, plane=blockIdx.z;
  long pbase=(long)plane*65536;
  f4 P1[2][2],P2[2][2],P3[2][2],P4[2][2];
  #pragma unroll
  for(int i=0;i<2;i++) for(int j=0;j<2;j++){ P1[i][j]=z4();P2[i][j]=z4();P3[i][j]=z4();P4[i][j]=z4(); }
  us8 pch, psh, pgr, pgi, pcl, psl;
  ldt(&pch, ach_, (long)m0*256, 256, 1, t);
  ldt(&psh, ash_, (long)m0*256, 256, 1, t);
  if constexpr(LO){
    ldt(&pcl, acl_, (long)m0*256, 256, 1, t);
    ldt(&psl, asl_, (long)m0*256, 256, 1, t);
  }
  ldt(&pgr, Br_, pbase+(long)n0*256, 256, 1, t);
  ldt(&pgi, Bi_, pbase+(long)n0*256, 256, 1, t);
  for(int k0=0;k0<256;k0+=32){
    __syncthreads();
    stt(Ach,&pch,1,t); stt(Ash,&psh,1,t);
    if constexpr(LO){ stt(Acl,&pcl,1,t); stt(Asl,&psl,1,t); }
    stt(Bgr,&pgr,1,t); stt(Bgi,&pgi,1,t);
    if(k0+32 < 256){
      ldt(&pch, ach_, (long)m0*256+k0+32, 256, 1, t);
      ldt(&psh, ash_, (long)m0*256+k0+32, 256, 1, t);
      if constexpr(LO){
        ldt(&pcl, acl_, (long)m0*256+k0+32, 256, 1, t);
        ldt(&psl, asl_, (long)m0*256+k0+32, 256, 1, t);
      }
      ldt(&pgr, Br_, pbase+(long)n0*256+k0+32, 256, 1, t);
      ldt(&pgi, Bi_, pbase+(long)n0*256+k0+32, 256, 1, t);
    }
    __syncthreads();
    int lr=l&15, g=l>>4;
    us8 fch[2],fsh[2],fcl[2],fsl[2];
    #pragma unroll
    for(int mm=0;mm<2;mm++){
      int rr=wr*32+mm*16+lr;
      fch[mm]=frg(Ach,rr,g); fsh[mm]=frg(Ash,rr,g);
      if constexpr(LO){ fcl[mm]=frg(Acl,rr,g); fsl[mm]=frg(Asl,rr,g); }
    }
    #pragma unroll
    for(int nn=0;nn<2;nn++){
      int rn=wc*32+nn*16+lr;
      us8 bgr=frg(Bgr,rn,g), bgi=frg(Bgi,rn,g);
      #pragma unroll
      for(int mm=0;mm<2;mm++){
        P1[mm][nn]=MF(fch[mm],bgr,P1[mm][nn]);
        P2[mm][nn]=MF(fsh[mm],bgi,P2[mm][nn]);
        P3[mm][nn]=MF(fch[mm],bgi,P3[mm][nn]);
        P4[mm][nn]=MF(fsh[mm],bgr,P4[mm][nn]);
        if constexpr(LO){
          P1[mm][nn]=MF(fcl[mm],bgr,P1[mm][nn]);
          P2[mm][nn]=MF(fsl[mm],bgi,P2[mm][nn]);
          P3[mm][nn]=MF(fcl[mm],bgi,P3[mm][nn]);
          P4[mm][nn]=MF(fsl[mm],bgr,P4[mm][nn]);
        }
      }
    }
  }
  int f32 = filt ? *flagp : 0;
  int lr=l&15, g=l>>4;
  int c_ch = plane & 127;
  #pragma unroll
  for(int nn=0;nn<2;nn++){
    int n = n0 + wc*32 + nn*16 + lr;
    #pragma unroll
    for(int mm=0;mm<2;mm++){
      int mb = m0 + wr*32 + mm*16 + (g<<2);
      float vr[4], vi[4];
      #pragma unroll
      for(int r=0;r<4;r++){
        vr[r] = P1[mm][nn][r] + sgn*P2[mm][nn][r];
        vi[r] = P3[mm][nn][r] - sgn*P4[mm][nn][r];
      }
      if(filt){
        #pragma unroll
        for(int r=0;r<4;r++){
          long fi = (((long)c_ch*256 + (mb+r))*256 + n)*2;
          float fwr=ldin(filt,fi,f32), fwi=ldin(filt,fi+1,f32);
          float a=vr[r], b=vi[r];
          vr[r]=a*fwr-b*fwi; vi[r]=a*fwi+b*fwr;
        }
      }
      if constexpr(TR){
        us4 pr, pi;
        #pragma unroll
        for(int r=0;r<4;r++){ pr[r]=f2u(vr[r]); pi[r]=f2u(vi[r]); }
        *(us4*)(Or_ + pbase + (long)n*256 + mb) = pr;
        *(us4*)(Oi_ + pbase + (long)n*256 + mb) = pi;
      } else {
        #pragma unroll
        for(int r=0;r<4;r++){
          Or_[pbase + (long)(mb+r)*256 + n] = f2u(vr[r]);
          Oi_[pbase + (long)(mb+r)*256 + n] = f2u(vi[r]);
        }
      }
    }
  }
}

// ---------------------------------------------------------------- row variance (transposed layout)
__global__ __launch_bounds__(1024) void k_var2(const u16t* __restrict__ Grt,
    const u16t* __restrict__ Git, float* __restrict__ rinv){
  __shared__ float rs[1024], is_[1024], qs[1024];
  int plane = blockIdx.x, t = threadIdx.x;
  int kh = t & 255, part = t >> 8;
  long base = (long)plane*65536 + kh;
  float sr=0.f, si=0.f, s2=0.f;
  #pragma unroll 4
  for(int q=0;q<64;q++){
    long o = base + (long)(part*64+q)*256;
    float r = u2f(Grt[o]), im = u2f(Git[o]);
    sr += r; si += im; s2 += r*r + im*im;
  }
  rs[t]=sr; is_[t]=si; qs[t]=s2;
  __syncthreads();
  if(t<256){
    sr = rs[t]+rs[t+256]+rs[t+512]+rs[t+768];
    si = is_[t]+is_[t+256]+is_[t+512]+is_[t+768];
    s2 = qs[t]+qs[t+256]+qs[t+512]+qs[t+768];
    float mr = sr*(1.f/256.f), mi = si*(1.f/256.f);
    float v = s2*(1.f/256.f) - mr*mr - mi*mi;
    rinv[plane*256 + kh] = rsqrtf(6.283185307179586f * fmaxf(v, 1e-20f));
  }
}

// ---------------------------------------------------------------- scores (MFMA, T14) + sigmoid
__global__ __launch_bounds__(256) void k_scores2(
    const u16t* __restrict__ Agr_, const u16t* __restrict__ Agi_,
    const u16t* __restrict__ Bxr_, const u16t* __restrict__ Bxi_,
    const float* __restrict__ rinv, u16t* __restrict__ Sr_, u16t* __restrict__ Si_){
  __shared__ __align__(16) u16t Agr[2048], Agi[2048], Bxr[2048], Bxi[2048];
  int t=threadIdx.x, l=t&63, wid=t>>6, wr=wid>>1, wc=wid&1;
  int m0=blockIdx.x*64, n0=blockIdx.y*64, plane=blockIdx.z;
  long pbase=(long)plane*65536;
  f4 P1[2][2],P2[2][2],P3[2][2],P4[2][2];
  #pragma unroll
  for(int i=0;i<2;i++) for(int j=0;j<2;j++){ P1[i][j]=z4();P2[i][j]=z4();P3[i][j]=z4();P4[i][j]=z4(); }
  us8 p0,p1,p2,p3;
  ldt(&p0, Agr_, pbase+(long)m0*256, 256, 1, t);
  ldt(&p1, Agi_, pbase+(long)m0*256, 256, 1, t);
  ldt(&p2, Bxr_, pbase+(long)n0*256, 256, 1, t);
  ldt(&p3, Bxi_, pbase+(long)n0*256, 256, 1, t);
  for(int k0=0;k0<256;k0+=32){
    __syncthreads();
    stt(Agr,&p0,1,t); stt(Agi,&p1,1,t); stt(Bxr,&p2,1,t); stt(Bxi,&p3,1,t);
    if(k0+32 < 256){
      ldt(&p0, Agr_, pbase+(long)m0*256+k0+32, 256, 1, t);
      ldt(&p1, Agi_, pbase+(long)m0*256+k0+32, 256, 1, t);
      ldt(&p2, Bxr_, pbase+(long)n0*256+k0+32, 256, 1, t);
      ldt(&p3, Bxi_, pbase+(long)n0*256+k0+32, 256, 1, t);
    }
    __syncthreads();
    int lr=l&15, g=l>>4;
    us8 agr[2], agi[2];
    #pragma unroll
    for(int mm=0;mm<2;mm++){
      int rr=wr*32+mm*16+lr;
      agr[mm]=frg(Agr,rr,g); agi[mm]=frg(Agi,rr,g);
    }
    #pragma unroll
    for(int nn=0;nn<2;nn++){
      int rn=wc*32+nn*16+lr;
      us8 bxr=frg(Bxr,rn,g), bxi=frg(Bxi,rn,g);
      #pragma unroll
      for(int mm=0;mm<2;mm++){
        P1[mm][nn]=MF(agr[mm],bxr,P1[mm][nn]);
        P2[mm][nn]=MF(agi[mm],bxi,P2[mm][nn]);
        P3[mm][nn]=MF(agr[mm],bxi,P3[mm][nn]);
        P4[mm][nn]=MF(agi[mm],bxr,P4[mm][nn]);
      }
    }
  }
  int lr=l&15, g=l>>4;
  #pragma unroll
  for(int nn=0;nn<2;nn++){
    int n = n0 + wc*32 + nn*16 + lr;
    #pragma unroll
    for(int mm=0;mm<2;mm++){
      int mb = m0 + wr*32 + mm*16 + (g<<2);
      us4 pr, pi;
      #pragma unroll
      for(int r=0;r<4;r++){
        float rv = rinv[(plane<<8) + mb + r];
        pr[r] = f2u(sigm((P1[mm][nn][r]-P2[mm][nn][r])*rv));
        pi[r] = f2u(sigm((P3[mm][nn][r]+P4[mm][nn][r])*rv));
      }
      *(us4*)(Sr_ + pbase + (long)n*256 + mb) = pr;
      *(us4*)(Si_ + pbase + (long)n*256 + mb) = pi;
    }
  }
}

// ---------------------------------------------------------------- irfft along W (MFMA, T14) + add x
// hi-only inverse tables: table-lo precision is below the bf16 data noise floor.
__global__ __launch_bounds__(256) void k_irfft2(
    const u16t* __restrict__ Tr, const u16t* __restrict__ Ti,
    const u16t* __restrict__ tic, const u16t* __restrict__ tis,
    const void* __restrict__ xin, const int* __restrict__ flagp, float* __restrict__ R){
  __shared__ __align__(16) u16t Ar[4096], Ai[4096], Bc[4096], Bs[4096];
  int t=threadIdx.x, l=t&63, wid=t>>6, wr=wid>>1, wc=wid&1;
  int m0=blockIdx.x*128, n0=blockIdx.y*128;
  f4 acc[4][4];
  #pragma unroll
  for(int i=0;i<4;i++) for(int j=0;j<4;j++) acc[i][j]=z4();
  us8 pr2[2], pi2[2], pc2[2], ps2[2];
  ldt(pr2, Tr,  (long)m0*256, 256, 2, t);
  ldt(pi2, Ti,  (long)m0*256, 256, 2, t);
  ldt(pc2, tic, (long)n0*256, 256, 2, t);
  ldt(ps2, tis, (long)n0*256, 256, 2, t);
  for(int k0=0;k0<256;k0+=32){
    __syncthreads();
    stt(Ar,pr2,2,t); stt(Ai,pi2,2,t); stt(Bc,pc2,2,t); stt(Bs,ps2,2,t);
    if(k0+32 < 256){
      ldt(pr2, Tr,  (long)m0*256+k0+32, 256, 2, t);
      ldt(pi2, Ti,  (long)m0*256+k0+32, 256, 2, t);
      ldt(pc2, tic, (long)n0*256+k0+32, 256, 2, t);
      ldt(ps2, tis, (long)n0*256+k0+32, 256, 2, t);
    }
    __syncthreads();
    int lr=l&15, g=l>>4;
    us8 ar[4], ai2[4];
    #pragma unroll
    for(int mm=0;mm<4;mm++){
      int rr = wr*64+mm*16+lr;
      ar[mm]=frg(Ar,rr,g); ai2[mm]=frg(Ai,rr,g);
    }
    #pragma unroll
    for(int nn=0;nn<4;nn++){
      int rn = wc*64+nn*16+lr;
      us8 bc=frg(Bc,rn,g), bs=frg(Bs,rn,g);
      #pragma unroll
      for(int mm=0;mm<4;mm++){
        acc[mm][nn]=MF(ar[mm],bc,acc[mm][nn]);
        acc[mm][nn]=MF(ai2[mm],bs,acc[mm][nn]);
      }
    }
  }
  int f32=*flagp;
  int lr=l&15, g=l>>4;
  #pragma unroll
  for(int nn=0;nn<4;nn++){
    int w = n0 + wc*64 + nn*16 + lr;
    if(w >= 510) continue;
    #pragma unroll
    for(int mm=0;mm<4;mm++){
      int row0 = m0 + wr*64 + mm*16 + (g<<2);
      #pragma unroll
      for(int r=0;r<4;r++){
        long o = (long)(row0+r)*510 + w;
        R[o] = acc[mm][nn][r] + ldin(xin, o, f32);
      }
    }
  }
}

// ---------------------------------------------------------------- channel LayerNorm
__global__ __launch_bounds__(256) void k_ln(const float* __restrict__ R,
    const void* __restrict__ gamma, const void* __restrict__ beta,
    const int* __restrict__ flagp, void* __restrict__ out){
  int f32 = *flagp;
  int p = blockIdx.x*256 + threadIdx.x;
  int b = p / HWP, hw = p % HWP;
  long base = (long)b*CCH*HWP + hw;
  float sum=0.f, sq=0.f;
  for(int c=0;c<CCH;c++){
    float v = R[base + (long)c*HWP];
    sum += v; sq += v*v;
  }
  float mu = sum*(1.f/128.f);
  float var = sq*(1.f/128.f) - mu*mu;
  float inv = rsqrtf(fmaxf(var,0.f) + 1e-6f);
  for(int c=0;c<CCH;c++){
    float v = (R[base + (long)c*HWP] - mu)*inv;
    float o = ldin(gamma,c,f32)*v + ldin(beta,c,f32);
    long oi = base + (long)c*HWP;
    if(f32) ((float*)out)[oi] = o;
    else    ((u16t*)out)[oi]  = f2u(o);
  }
}

// ================================================================ launcher
extern "C" void kernel_launch(void* const* d_in, const int* in_sizes, int n_in,
                              void* d_out, int out_size, void* d_ws, size_t ws_size,
                              hipStream_t stream) {
  const void* g   = d_in[0];
  const void* x   = d_in[1];
  const void* wg  = d_in[2];
  const void* bg  = d_in[3];
  const void* wx  = d_in[4];
  const void* bx  = d_in[5];
  const void* fg  = d_in[6];
  const void* fx  = d_in[7];
  const void* gam = d_in[8];
  const void* bet = d_in[9];

  // workspace carve (~204.2 MB)
  u16t* Y  = (u16t*)d_ws;            // [65536][512] padded conv out; later X2t; later part of R
  u16t* Bq = Y  + 33554432L;         // G1t / attenT (re,im = +0, +UPL)
  u16t* Cq = Bq + 33554432L;         // G2t / T     (re,im)
  char* pp = (char*)d_ws + 201326592L;
  float* rinv = (float*)pp; pp += 262144L;
  u16t* twch=(u16t*)pp; pp+=262144L;  u16t* twcl=(u16t*)pp; pp+=262144L;
  u16t* twsh=(u16t*)pp; pp+=262144L;  u16t* twsl=(u16t*)pp; pp+=262144L;
  u16t* thch=(u16t*)pp; pp+=131072L;  u16t* thcl=(u16t*)pp; pp+=131072L;
  u16t* thsh=(u16t*)pp; pp+=131072L;  u16t* thsl=(u16t*)pp; pp+=131072L;
  u16t* tich=(u16t*)pp; pp+=262144L;  u16t* ticl=(u16t*)pp; pp+=262144L;
  u16t* tish=(u16t*)pp; pp+=262144L;  u16t* tisl=(u16t*)pp; pp+=262144L;
  int* flag = (int*)pp;
  float* R  = (float*)d_ws;          // overlays Y+Bq (both dead by then)

  k_detect <<<1,256,0,stream>>>(g, flag);
  k_tables2<<<512,256,0,stream>>>(twch,twcl,twsh,twsl,thch,thcl,thsh,thsl,tich,ticl,tish,tisl);
  k_zpad   <<<512,256,0,stream>>>(Y);

  // --- g path: conv -> rfft_W (writes G1t) -> FFT_H * filter (writes G2t) => Cq
  k_conv2<<<dim3(1020,2),256,0,stream>>>(g, wg, bg, flag, Y);
  k_rfft2<<<dim3(512,2),256,0,stream>>>(Y, twch,twcl,twsh,twsl, Bq, Bq+UPL);
  k_ffth2<1,1><<<dim3(4,4,256),256,0,stream>>>(Bq, Bq+UPL, thch,thcl,thsh,thsl, 1.f, fg, flag, Cq, Cq+UPL);

  // --- x path => X2t into Y region (Y dead after rfft)
  k_conv2<<<dim3(1020,2),256,0,stream>>>(x, wx, bx, flag, Y);
  k_rfft2<<<dim3(512,2),256,0,stream>>>(Y, twch,twcl,twsh,twsl, Bq, Bq+UPL);
  k_ffth2<1,1><<<dim3(4,4,256),256,0,stream>>>(Bq, Bq+UPL, thch,thcl,thsh,thsl, 1.f, fx, flag, Y, Y+UPL);

  // --- variance of G2 rows (columns of G2t) -> rinv
  k_var2<<<256,1024,0,stream>>>(Cq, Cq+UPL, rinv);

  // --- scores + sigmoid => attenT in Bq
  k_scores2<<<dim3(4,4,256),256,0,stream>>>(Cq, Cq+UPL, Y, Y+UPL, rinv, Bq, Bq+UPL);

  // --- inverse FFT along H => T (natural layout) in Cq  (hi-only tables)
  k_ffth2<0,0><<<dim3(4,4,256),256,0,stream>>>(Bq, Bq+UPL, thch,thcl,thsh,thsl, -1.f, nullptr, flag, Cq, Cq+UPL);

  // --- inverse rfft along W, + x  => R (f32)  (hi-only tables)
  k_irfft2<<<dim3(512,4),256,0,stream>>>(Cq, Cq+UPL, tich,tish, x, flag, R);

  // --- channel LayerNorm => out
  k_ln<<<1020,256,0,stream>>>(R, gam, bet, flag, d_out);
}